// Round 1
// baseline (1739.069 us; speedup 1.0000x reference)
//
#include <hip/hip_runtime.h>
#include <cstdint>
#include <cstddef>

// ---------------------------------------------------------------------------
// QuantMlp: out = fq(gelu(fq(x[reorder]) @ W1^T + b1)) @ W2^T + b2
// fq = per-token symmetric int8 fake-quant. We exploit that fq's output is
// q * scale with q in [-128,127]: store q exactly in bf16 and fold scale into
// the GEMM epilogue, so A-side has ZERO representation error.
// ---------------------------------------------------------------------------

typedef __attribute__((ext_vector_type(8))) short short8;   // 8 bf16 (4 VGPRs)
typedef __attribute__((ext_vector_type(4))) float f32x4;

__device__ __forceinline__ float bf2f(unsigned short u) {
    return __uint_as_float(((unsigned)u) << 16);
}
__device__ __forceinline__ unsigned short f2bf(float f) {
    unsigned u = __float_as_uint(f);
    u += 0x7fff + ((u >> 16) & 1);   // round-to-nearest-even
    return (unsigned short)(u >> 16);
}

// async global->LDS, 16B per lane; LDS dest is wave-uniform base + lane*16
__device__ __forceinline__ void gload_lds16(const void* gptr, void* ldsptr) {
    typedef __attribute__((address_space(1))) const unsigned int gu32;
    typedef __attribute__((address_space(3))) unsigned int lu32;
    __builtin_amdgcn_global_load_lds((gu32*)gptr, (lu32*)ldsptr, 16, 0, 0);
}

// ---------------------------------------------------------------------------
// GEMM: C[m][n] = rowScale[m] * sum_k A[m][k]*B[n][k] + bias[n]
// A: [M,K] bf16 row-major, B: [N,K] bf16 row-major (TN — both K-contiguous).
// GELU=true: apply exact-erf GELU, store bf16. else: store fp32.
// Block: 256 thr = 4 waves in 2x2, each wave 64x64 via 4x4 mfma 16x16x32.
// Tile: BM=BN=128, BK=64. LDS 32 KB, single-buffered (m97 structure).
// ---------------------------------------------------------------------------
template <bool GELU>
__global__ __launch_bounds__(256) void gemm_bt(
    const unsigned short* __restrict__ A, const unsigned short* __restrict__ B,
    const float* __restrict__ bias, const float* __restrict__ rowScale,
    void* __restrict__ C, int M, int N, int K)
{
    __shared__ unsigned short lA[128 * 64];
    __shared__ unsigned short lB[128 * 64];

    const int tid  = threadIdx.x;
    const int lane = tid & 63;
    const int wave = tid >> 6;
    const int wm = wave >> 1;          // 0..1
    const int wn = wave & 1;           // 0..1
    const int bn = blockIdx.x;         // N fastest -> A-tile LLC reuse
    const int bm = blockIdx.y;

    const unsigned short* Ab = A + (size_t)bm * 128 * K;
    const unsigned short* Bb = B + (size_t)bn * 128 * K;

    f32x4 acc[4][4];
    const f32x4 zero = {0.f, 0.f, 0.f, 0.f};
#pragma unroll
    for (int i = 0; i < 4; ++i)
#pragma unroll
        for (int j = 0; j < 4; ++j) acc[i][j] = zero;

    const int q  = lane >> 4;          // quad 0..3
    const int lr = lane & 15;
    const int wbase = tid & 0xFFC0;    // wave*64 (wave-uniform)

    const int nk = K >> 6;
    for (int kb = 0; kb < nk; ++kb) {
        const unsigned short* Ak = Ab + kb * 64;
        const unsigned short* Bk = Bb + kb * 64;
        // stage A,B tiles: 1024 chunks of 16B each, 4 per thread per matrix
#pragma unroll
        for (int i = 0; i < 4; ++i) {
            int idx = i * 256 + tid;
            int r = idx >> 3, c = (idx & 7) << 3;
            gload_lds16(Ak + (size_t)r * K + c, &lA[(i * 256 + wbase) * 8]);
        }
#pragma unroll
        for (int i = 0; i < 4; ++i) {
            int idx = i * 256 + tid;
            int r = idx >> 3, c = (idx & 7) << 3;
            gload_lds16(Bk + (size_t)r * K + c, &lB[(i * 256 + wbase) * 8]);
        }
        __syncthreads();   // drains vmcnt for global_load_lds

#pragma unroll
        for (int ks = 0; ks < 2; ++ks) {
            short8 af[4], bfr[4];
#pragma unroll
            for (int i = 0; i < 4; ++i)
                af[i] = *(const short8*)&lA[(wm * 64 + i * 16 + lr) * 64 + ks * 32 + q * 8];
#pragma unroll
            for (int j = 0; j < 4; ++j)
                bfr[j] = *(const short8*)&lB[(wn * 64 + j * 16 + lr) * 64 + ks * 32 + q * 8];
#pragma unroll
            for (int i = 0; i < 4; ++i)
#pragma unroll
                for (int j = 0; j < 4; ++j)
                    acc[i][j] = __builtin_amdgcn_mfma_f32_16x16x32_bf16(
                        af[i], bfr[j], acc[i][j], 0, 0, 0);
        }
        __syncthreads();
    }

    // epilogue: C/D layout col=lane&15 (n), row=quad*4+reg (m)
#pragma unroll
    for (int i = 0; i < 4; ++i) {
#pragma unroll
        for (int r = 0; r < 4; ++r) {
            int m = bm * 128 + wm * 64 + i * 16 + q * 4 + r;
            float sc = rowScale[m];
#pragma unroll
            for (int j = 0; j < 4; ++j) {
                int n = bn * 128 + wn * 64 + j * 16 + lr;
                float v = acc[i][j][r] * sc + bias[n];
                size_t off = (size_t)m * N + n;
                if (GELU) {
                    v = 0.5f * v * (1.f + erff(v * 0.70710678118654752f));
                    ((unsigned short*)C)[off] = f2bf(v);
                } else {
                    ((float*)C)[off] = v;
                }
            }
        }
    }
}

__device__ __forceinline__ float waveMax(float m) {
#pragma unroll
    for (int off = 32; off; off >>= 1) m = fmaxf(m, __shfl_xor(m, off));
    return m;
}

// per-token: gather reorder, absmax, write q (exact in bf16) + scale
__global__ __launch_bounds__(256) void quant_x_kernel(
    const float* __restrict__ x, const int* __restrict__ ridx,
    unsigned short* __restrict__ xq, float* __restrict__ sx, int D)
{
    __shared__ float buf[1152];
    __shared__ float wmax[4];
    const float* xr = x + (size_t)blockIdx.x * D;
    const int tid = threadIdx.x;
    float m = 0.f;
    for (int c = tid; c < D; c += 256) {
        float v = xr[ridx[c]];
        buf[c] = v;
        m = fmaxf(m, fabsf(v));
    }
    m = waveMax(m);
    if ((tid & 63) == 0) wmax[tid >> 6] = m;
    __syncthreads();
    m = fmaxf(fmaxf(wmax[0], wmax[1]), fmaxf(wmax[2], wmax[3]));
    float scale = fmaxf(m * (1.f / 127.f), 1e-8f);
    float inv = 1.f / scale;
    unsigned short* xo = xq + (size_t)blockIdx.x * D;
    for (int c = tid; c < D; c += 256) {
        float qv = fminf(fmaxf(rintf(buf[c] * inv), -128.f), 127.f);
        xo[c] = f2bf(qv);  // exact: integers |q|<=128
    }
    if (tid == 0) sx[blockIdx.x] = scale;
}

// per-token in-place: h(bf16) -> q (exact bf16) + scale
__global__ __launch_bounds__(256) void quant_h_kernel(
    unsigned short* __restrict__ h, float* __restrict__ sh, int H)
{
    __shared__ float buf[4608];
    __shared__ float wmax[4];
    unsigned int* hr = (unsigned int*)(h + (size_t)blockIdx.x * H);
    const int tid = threadIdx.x;
    const int n2 = H >> 1;
    float m = 0.f;
    for (int c = tid; c < n2; c += 256) {
        unsigned int u = hr[c];
        float v0 = bf2f((unsigned short)(u & 0xffffu));
        float v1 = bf2f((unsigned short)(u >> 16));
        buf[2 * c] = v0; buf[2 * c + 1] = v1;
        m = fmaxf(m, fmaxf(fabsf(v0), fabsf(v1)));
    }
    m = waveMax(m);
    if ((tid & 63) == 0) wmax[tid >> 6] = m;
    __syncthreads();
    m = fmaxf(fmaxf(wmax[0], wmax[1]), fmaxf(wmax[2], wmax[3]));
    float scale = fmaxf(m * (1.f / 127.f), 1e-8f);
    float inv = 1.f / scale;
    for (int c = tid; c < n2; c += 256) {
        float q0 = fminf(fmaxf(rintf(buf[2 * c] * inv), -128.f), 127.f);
        float q1 = fminf(fmaxf(rintf(buf[2 * c + 1] * inv), -128.f), 127.f);
        hr[c] = (unsigned int)f2bf(q0) | ((unsigned int)f2bf(q1) << 16);
    }
    if (tid == 0) sh[blockIdx.x] = scale;
}

__global__ __launch_bounds__(256) void cvt_f32_bf16(
    const float* __restrict__ src, unsigned short* __restrict__ dst, long long n)
{
    long long i = ((long long)blockIdx.x * 256 + threadIdx.x) * 4;
    long long stride = (long long)gridDim.x * 1024;
    for (; i < n; i += stride) {
        float4 v = *(const float4*)(src + i);
        ushort4 o;
        o.x = f2bf(v.x); o.y = f2bf(v.y); o.z = f2bf(v.z); o.w = f2bf(v.w);
        *(ushort4*)(dst + i) = o;
    }
}

extern "C" void kernel_launch(void* const* d_in, const int* in_sizes, int n_in,
                              void* d_out, int out_size, void* d_ws, size_t ws_size,
                              hipStream_t stream)
{
    const float* x    = (const float*)d_in[0];
    const int*   ridx = (const int*)d_in[1];
    const float* W1   = (const float*)d_in[2];
    const float* b1   = (const float*)d_in[3];
    const float* W2   = (const float*)d_in[4];
    const float* b2   = (const float*)d_in[5];
    float* out = (float*)d_out;

    const long long D = in_sizes[1];                 // 1152
    const long long H = in_sizes[3];                 // 4608
    const long long M = (long long)in_sizes[0] / D;  // 32768

    auto al = [](size_t v) { return (v + 255) & ~(size_t)255; };
    char* p = (char*)d_ws;
    unsigned short* w1b = (unsigned short*)p; p += al((size_t)(H * D * 2));
    unsigned short* w2b = (unsigned short*)p; p += al((size_t)(D * H * 2));
    size_t used = (size_t)(p - (char*)d_ws);

    // chunk tokens so per-chunk xq/h/scales fit in remaining workspace
    size_t perTok = (size_t)(D + H) * 2 + 8;
    long long chunk = (long long)((ws_size - used - 4096) / perTok);
    chunk = (chunk / 128) * 128;
    if (chunk > M) chunk = M;
    if (chunk < 128) chunk = 128;  // guard (assumes ws >= ~24 MB)

    unsigned short* xq   = (unsigned short*)p; p += al((size_t)chunk * D * 2);
    unsigned short* hbuf = (unsigned short*)p; p += al((size_t)chunk * H * 2);
    float* sx = (float*)p; p += al((size_t)chunk * 4);
    float* sh = (float*)p;

    cvt_f32_bf16<<<dim3((unsigned)((H * D) / 1024)), 256, 0, stream>>>(W1, w1b, H * D);
    cvt_f32_bf16<<<dim3((unsigned)((D * H) / 1024)), 256, 0, stream>>>(W2, w2b, D * H);

    for (long long r0 = 0; r0 < M; r0 += chunk) {
        long long mc = M - r0; if (mc > chunk) mc = chunk;
        quant_x_kernel<<<dim3((unsigned)mc), 256, 0, stream>>>(
            x + r0 * D, ridx, xq, sx, (int)D);
        gemm_bt<true><<<dim3((unsigned)(H / 128), (unsigned)(mc / 128)), 256, 0, stream>>>(
            xq, w1b, b1, sx, hbuf, (int)mc, (int)H, (int)D);
        quant_h_kernel<<<dim3((unsigned)mc), 256, 0, stream>>>(hbuf, sh, (int)H);
        gemm_bt<false><<<dim3((unsigned)(D / 128), (unsigned)(mc / 128)), 256, 0, stream>>>(
            hbuf, w2b, b2, sh, out + r0 * D, (int)mc, (int)D, (int)H);
    }
}

// Round 2
// 1510.517 us; speedup vs baseline: 1.1513x; 1.1513x over previous
//
#include <hip/hip_runtime.h>
#include <cstdint>
#include <cstddef>

// ---------------------------------------------------------------------------
// QuantMlp: out = fq(gelu(fq(x[reorder]) @ W1^T + b1)) @ W2^T + b2
// fq = per-token symmetric int8 fake-quant. fq's output is q*scale with
// q in [-128,127]: store q exactly in bf16, fold scale into GEMM epilogue.
//
// R1: XOR-swizzled LDS layout (16B-chunk granularity) to kill the 16-way
// bank conflict on ds_read_b128 fragment reads (row stride was 128B = 32
// banks). global_load_lds dest is fixed (base+lane*16), so the swizzle is
// applied by inverting it on the per-lane GLOBAL source address.
// ---------------------------------------------------------------------------

typedef __attribute__((ext_vector_type(8))) short short8;   // 8 bf16 (4 VGPRs)
typedef __attribute__((ext_vector_type(4))) float f32x4;

__device__ __forceinline__ float bf2f(unsigned short u) {
    return __uint_as_float(((unsigned)u) << 16);
}
__device__ __forceinline__ unsigned short f2bf(float f) {
    unsigned u = __float_as_uint(f);
    u += 0x7fff + ((u >> 16) & 1);   // round-to-nearest-even
    return (unsigned short)(u >> 16);
}

// async global->LDS, 16B per lane; LDS dest is wave-uniform base + lane*16
__device__ __forceinline__ void gload_lds16(const void* gptr, void* ldsptr) {
    typedef __attribute__((address_space(1))) const unsigned int gu32;
    typedef __attribute__((address_space(3))) unsigned int lu32;
    __builtin_amdgcn_global_load_lds((gu32*)gptr, (lu32*)ldsptr, 16, 0, 0);
}

// ---------------------------------------------------------------------------
// GEMM: C[m][n] = rowScale[m] * sum_k A[m][k]*B[n][k] + bias[n]
// A: [M,K] bf16 row-major, B: [N,K] bf16 row-major (TN — both K-contiguous).
// GELU=true: apply exact-erf GELU, store bf16. else: store fp32.
// Block: 256 thr = 4 waves in 2x2, each wave 64x64 via 4x4 mfma 16x16x32.
// Tile: BM=BN=128, BK=64. LDS 32 KB, single-buffered (m97 structure).
// LDS layout: row r of a tile is 8 chunks of 16B; chunk slot sc holds global
// chunk (sc ^ (r&7)).
// ---------------------------------------------------------------------------
template <bool GELU>
__global__ __launch_bounds__(256) void gemm_bt(
    const unsigned short* __restrict__ A, const unsigned short* __restrict__ B,
    const float* __restrict__ bias, const float* __restrict__ rowScale,
    void* __restrict__ C, int M, int N, int K)
{
    __shared__ unsigned short lA[128 * 64];
    __shared__ unsigned short lB[128 * 64];

    const int tid  = threadIdx.x;
    const int lane = tid & 63;
    const int wave = tid >> 6;
    const int wm = wave >> 1;          // 0..1
    const int wn = wave & 1;           // 0..1
    const int bn = blockIdx.x;         // N fastest -> A-tile LLC reuse
    const int bm = blockIdx.y;

    const unsigned short* Ab = A + (size_t)bm * 128 * K;
    const unsigned short* Bb = B + (size_t)bn * 128 * K;

    f32x4 acc[4][4];
    const f32x4 zero = {0.f, 0.f, 0.f, 0.f};
#pragma unroll
    for (int i = 0; i < 4; ++i)
#pragma unroll
        for (int j = 0; j < 4; ++j) acc[i][j] = zero;

    const int q  = lane >> 4;          // quad 0..3
    const int lr = lane & 15;
    const int wbase = tid & 0xFFC0;    // wave*64 (wave-uniform)

    const int nk = K >> 6;
    for (int kb = 0; kb < nk; ++kb) {
        const unsigned short* Ak = Ab + kb * 64;
        const unsigned short* Bk = Bb + kb * 64;
        // stage A,B tiles: 1024 chunks of 16B each, 4 per thread per matrix.
        // lane's fixed LDS slot idx -> load the chunk the swizzle maps there.
#pragma unroll
        for (int i = 0; i < 4; ++i) {
            int idx = i * 256 + tid;
            int r = idx >> 3, sc = idx & 7;
            int c = (sc ^ (r & 7)) << 3;
            gload_lds16(Ak + (size_t)r * K + c, &lA[(i * 256 + wbase) * 8]);
        }
#pragma unroll
        for (int i = 0; i < 4; ++i) {
            int idx = i * 256 + tid;
            int r = idx >> 3, sc = idx & 7;
            int c = (sc ^ (r & 7)) << 3;
            gload_lds16(Bk + (size_t)r * K + c, &lB[(i * 256 + wbase) * 8]);
        }
        __syncthreads();   // drains vmcnt for global_load_lds

#pragma unroll
        for (int ks = 0; ks < 2; ++ks) {
            short8 af[4], bfr[4];
            const int c8 = ks * 4 + q;           // 16B-chunk column 0..7
#pragma unroll
            for (int i = 0; i < 4; ++i) {
                int R = wm * 64 + i * 16 + lr;
                af[i] = *(const short8*)&lA[R * 64 + ((c8 ^ (R & 7)) << 3)];
            }
#pragma unroll
            for (int j = 0; j < 4; ++j) {
                int R = wn * 64 + j * 16 + lr;
                bfr[j] = *(const short8*)&lB[R * 64 + ((c8 ^ (R & 7)) << 3)];
            }
#pragma unroll
            for (int i = 0; i < 4; ++i)
#pragma unroll
                for (int j = 0; j < 4; ++j)
                    acc[i][j] = __builtin_amdgcn_mfma_f32_16x16x32_bf16(
                        af[i], bfr[j], acc[i][j], 0, 0, 0);
        }
        __syncthreads();
    }

    // epilogue: C/D layout col=lane&15 (n), row=quad*4+reg (m)
#pragma unroll
    for (int i = 0; i < 4; ++i) {
#pragma unroll
        for (int r = 0; r < 4; ++r) {
            int m = bm * 128 + wm * 64 + i * 16 + q * 4 + r;
            float sc = rowScale[m];
#pragma unroll
            for (int j = 0; j < 4; ++j) {
                int n = bn * 128 + wn * 64 + j * 16 + lr;
                float v = acc[i][j][r] * sc + bias[n];
                size_t off = (size_t)m * N + n;
                if (GELU) {
                    v = 0.5f * v * (1.f + erff(v * 0.70710678118654752f));
                    ((unsigned short*)C)[off] = f2bf(v);
                } else {
                    ((float*)C)[off] = v;
                }
            }
        }
    }
}

__device__ __forceinline__ float waveMax(float m) {
#pragma unroll
    for (int off = 32; off; off >>= 1) m = fmaxf(m, __shfl_xor(m, off));
    return m;
}

// per-token: gather reorder, absmax, write q (exact in bf16) + scale
__global__ __launch_bounds__(256) void quant_x_kernel(
    const float* __restrict__ x, const int* __restrict__ ridx,
    unsigned short* __restrict__ xq, float* __restrict__ sx, int D)
{
    __shared__ float buf[1152];
    __shared__ float wmax[4];
    const float* xr = x + (size_t)blockIdx.x * D;
    const int tid = threadIdx.x;
    float m = 0.f;
    for (int c = tid; c < D; c += 256) {
        float v = xr[ridx[c]];
        buf[c] = v;
        m = fmaxf(m, fabsf(v));
    }
    m = waveMax(m);
    if ((tid & 63) == 0) wmax[tid >> 6] = m;
    __syncthreads();
    m = fmaxf(fmaxf(wmax[0], wmax[1]), fmaxf(wmax[2], wmax[3]));
    float scale = fmaxf(m * (1.f / 127.f), 1e-8f);
    float inv = 1.f / scale;
    unsigned short* xo = xq + (size_t)blockIdx.x * D;
    for (int c = tid; c < D; c += 256) {
        float qv = fminf(fmaxf(rintf(buf[c] * inv), -128.f), 127.f);
        xo[c] = f2bf(qv);  // exact: integers |q|<=128
    }
    if (tid == 0) sx[blockIdx.x] = scale;
}

// per-token in-place: h(bf16) -> q (exact bf16) + scale
__global__ __launch_bounds__(256) void quant_h_kernel(
    unsigned short* __restrict__ h, float* __restrict__ sh, int H)
{
    __shared__ float buf[4608];
    __shared__ float wmax[4];
    unsigned int* hr = (unsigned int*)(h + (size_t)blockIdx.x * H);
    const int tid = threadIdx.x;
    const int n2 = H >> 1;
    float m = 0.f;
    for (int c = tid; c < n2; c += 256) {
        unsigned int u = hr[c];
        float v0 = bf2f((unsigned short)(u & 0xffffu));
        float v1 = bf2f((unsigned short)(u >> 16));
        buf[2 * c] = v0; buf[2 * c + 1] = v1;
        m = fmaxf(m, fmaxf(fabsf(v0), fabsf(v1)));
    }
    m = waveMax(m);
    if ((tid & 63) == 0) wmax[tid >> 6] = m;
    __syncthreads();
    m = fmaxf(fmaxf(wmax[0], wmax[1]), fmaxf(wmax[2], wmax[3]));
    float scale = fmaxf(m * (1.f / 127.f), 1e-8f);
    float inv = 1.f / scale;
    for (int c = tid; c < n2; c += 256) {
        float q0 = fminf(fmaxf(rintf(buf[2 * c] * inv), -128.f), 127.f);
        float q1 = fminf(fmaxf(rintf(buf[2 * c + 1] * inv), -128.f), 127.f);
        hr[c] = (unsigned int)f2bf(q0) | ((unsigned int)f2bf(q1) << 16);
    }
    if (tid == 0) sh[blockIdx.x] = scale;
}

__global__ __launch_bounds__(256) void cvt_f32_bf16(
    const float* __restrict__ src, unsigned short* __restrict__ dst, long long n)
{
    long long i = ((long long)blockIdx.x * 256 + threadIdx.x) * 4;
    long long stride = (long long)gridDim.x * 1024;
    for (; i < n; i += stride) {
        float4 v = *(const float4*)(src + i);
        ushort4 o;
        o.x = f2bf(v.x); o.y = f2bf(v.y); o.z = f2bf(v.z); o.w = f2bf(v.w);
        *(ushort4*)(dst + i) = o;
    }
}

extern "C" void kernel_launch(void* const* d_in, const int* in_sizes, int n_in,
                              void* d_out, int out_size, void* d_ws, size_t ws_size,
                              hipStream_t stream)
{
    const float* x    = (const float*)d_in[0];
    const int*   ridx = (const int*)d_in[1];
    const float* W1   = (const float*)d_in[2];
    const float* b1   = (const float*)d_in[3];
    const float* W2   = (const float*)d_in[4];
    const float* b2   = (const float*)d_in[5];
    float* out = (float*)d_out;

    const long long D = in_sizes[1];                 // 1152
    const long long H = in_sizes[3];                 // 4608
    const long long M = (long long)in_sizes[0] / D;  // 32768

    auto al = [](size_t v) { return (v + 255) & ~(size_t)255; };
    char* p = (char*)d_ws;
    unsigned short* w1b = (unsigned short*)p; p += al((size_t)(H * D * 2));
    unsigned short* w2b = (unsigned short*)p; p += al((size_t)(D * H * 2));
    size_t used = (size_t)(p - (char*)d_ws);

    // chunk tokens so per-chunk xq/h/scales fit in remaining workspace
    size_t perTok = (size_t)(D + H) * 2 + 8;
    long long chunk = (long long)((ws_size - used - 4096) / perTok);
    chunk = (chunk / 128) * 128;
    if (chunk > M) chunk = M;
    if (chunk < 128) chunk = 128;  // guard (assumes ws >= ~24 MB)

    unsigned short* xq   = (unsigned short*)p; p += al((size_t)chunk * D * 2);
    unsigned short* hbuf = (unsigned short*)p; p += al((size_t)chunk * H * 2);
    float* sx = (float*)p; p += al((size_t)chunk * 4);
    float* sh = (float*)p;

    cvt_f32_bf16<<<dim3((unsigned)((H * D) / 1024)), 256, 0, stream>>>(W1, w1b, H * D);
    cvt_f32_bf16<<<dim3((unsigned)((D * H) / 1024)), 256, 0, stream>>>(W2, w2b, D * H);

    for (long long r0 = 0; r0 < M; r0 += chunk) {
        long long mc = M - r0; if (mc > chunk) mc = chunk;
        quant_x_kernel<<<dim3((unsigned)mc), 256, 0, stream>>>(
            x + r0 * D, ridx, xq, sx, (int)D);
        gemm_bt<true><<<dim3((unsigned)(H / 128), (unsigned)(mc / 128)), 256, 0, stream>>>(
            xq, w1b, b1, sx, hbuf, (int)mc, (int)H, (int)D);
        quant_h_kernel<<<dim3((unsigned)mc), 256, 0, stream>>>(hbuf, sh, (int)H);
        gemm_bt<false><<<dim3((unsigned)(D / 128), (unsigned)(mc / 128)), 256, 0, stream>>>(
            hbuf, w2b, b2, sh, out + r0 * D, (int)mc, (int)D, (int)H);
    }
}